// Round 9
// baseline (528.515 us; speedup 1.0000x reference)
//
#include <hip/hip_runtime.h>

// x[T=4,B=32,N=1024,C=256] -> Linear -> BN -> LIF -> Linear -> BN -> LIF
// M = 131072 rows, fp32 in/out.
// GEMM2: spikes 0/1 (exact bf16) @ exact 3-term bf16 split of W2 (MFMA), r5 config.
// GEMM1 v3 (round 9): fp16 2-term split, 3 products; BM=128 x BN=128, 8 waves of
// 32x64; K-chunked LDS double-buffer (2 x 32KB, chunks of K=64) with issue-early /
// write-late staging pipeline; launch_bounds(512,4) -> 2 blocks/CU.

typedef __attribute__((ext_vector_type(8))) short bf16x8;
typedef __attribute__((ext_vector_type(8))) _Float16 f16x8;
typedef __attribute__((ext_vector_type(4))) _Float16 f16x4;
typedef __attribute__((ext_vector_type(4))) float f32x4;

__device__ __forceinline__ unsigned short f32_to_bf16_rne(float f) {
    unsigned int u = __builtin_bit_cast(unsigned int, f);
    u += 0x7FFFu + ((u >> 16) & 1u);
    return (unsigned short)(u >> 16);
}
__device__ __forceinline__ float bf16_to_f32(unsigned short h) {
    unsigned int u = ((unsigned int)h) << 16;
    return __builtin_bit_cast(float, u);
}

// -------- W1 split: W1[k][n] fp32 -> W1hiT/W1loT[n][k] fp16 (lo pre-scaled 2^12) -----
__global__ __launch_bounds__(256) void split_w1(const float* __restrict__ W1,
                                                _Float16* __restrict__ BhiT,
                                                _Float16* __restrict__ BloT) {
    int i = blockIdx.x * 256 + threadIdx.x;  // 65536
    int k = i >> 8, n = i & 255;
    float w = W1[i];
    _Float16 hi = (_Float16)w;
    _Float16 lo = (_Float16)((w - (float)hi) * 4096.0f);
    BhiT[(size_t)n * 256 + k] = hi;
    BloT[(size_t)n * 256 + k] = lo;
}

// -------- W2 split: W2[k][n] fp32 -> W2catT[t][n][k] bf16, t=hi/mid/lo (exact sum) ----
__global__ __launch_bounds__(256) void split_w2(const float* __restrict__ W2,
                                                unsigned short* __restrict__ Bt) {
    int i = blockIdx.x * 256 + threadIdx.x;  // 65536
    int k = i >> 8, n = i & 255;
    float w = W2[i];
    unsigned short hi = f32_to_bf16_rne(w);
    float r = w - bf16_to_f32(hi);
    unsigned short mid = f32_to_bf16_rne(r);
    float r2 = r - bf16_to_f32(mid);
    unsigned short lo = f32_to_bf16_rne(r2);
    Bt[(size_t)(0 * 256 + n) * 256 + k] = hi;
    Bt[(size_t)(1 * 256 + n) * 256 + k] = mid;
    Bt[(size_t)(2 * 256 + n) * 256 + k] = lo;
}

// ---------------- GEMM1 v3 (MFMA, fp16 2-split x 3 products) -------------------------
// grid 2048: bi=blk>>1 (m-tile 128), bj=blk&1 (n-tile 128). 8 waves: wr=wave>>1 (row
// group of 32), wc=wave&1 (col group of 64). K pipeline: 4 chunks of K=64, LDS dbuf.
__global__ __launch_bounds__(512, 4) void gemm1_mfma(const float* __restrict__ A,
                                                     const _Float16* __restrict__ Bhi,
                                                     const _Float16* __restrict__ Blo,
                                                     const float* __restrict__ bias,
                                                     float* __restrict__ C,
                                                     double* __restrict__ partial) {
    // 2 buffers x (hi 16KB + lo 16KB) = 64 KB. buffer stride 32768 B, lo at +16384.
    __shared__ __align__(16) char Alds[65536];
    const int bi = blockIdx.x >> 1;
    const int bj = blockIdx.x & 1;
    const size_t m0 = (size_t)bi * 128;
    const int n0 = bj * 128;
    const int tid = threadIdx.x;
    const int lane = tid & 63;
    const int wave = tid >> 6;   // 0..7
    const int wr = wave >> 1;    // 0..3
    const int wc = wave & 1;     // 0..1
    const int lrow = lane & 15, lchunk = lane >> 4;

    const int srow = tid >> 4, scolq = tid & 15;  // staging: 32 rows per it, 16 f4/row

    float4 ld[4];
#define LOADA(c)                                                              \
    _Pragma("unroll") for (int it = 0; it < 4; ++it) {                        \
        int row = it * 32 + srow;                                             \
        ld[it] = *(const float4*)(A + (m0 + row) * 256 + (c) * 64 + scolq * 4); \
    }
#define WRITEA(buf)                                                           \
    _Pragma("unroll") for (int it = 0; it < 4; ++it) {                        \
        int row = it * 32 + srow;                                             \
        float f0 = ld[it].x, f1 = ld[it].y, f2 = ld[it].z, f3 = ld[it].w;     \
        f16x4 hi4, lo4;                                                       \
        _Float16 h0 = (_Float16)f0; hi4[0] = h0; lo4[0] = (_Float16)((f0 - (float)h0) * 4096.0f); \
        _Float16 h1 = (_Float16)f1; hi4[1] = h1; lo4[1] = (_Float16)((f1 - (float)h1) * 4096.0f); \
        _Float16 h2 = (_Float16)f2; hi4[2] = h2; lo4[2] = (_Float16)((f2 - (float)h2) * 4096.0f); \
        _Float16 h3 = (_Float16)f3; hi4[3] = h3; lo4[3] = (_Float16)((f3 - (float)h3) * 4096.0f); \
        unsigned off = ((unsigned)row * 128u + (unsigned)scolq * 8u) ^ (((unsigned)row & 7u) << 4); \
        *(f16x4*)(Alds + (buf) * 32768 + off) = hi4;                          \
        *(f16x4*)(Alds + (buf) * 32768 + 16384 + off) = lo4;                  \
    }

    const _Float16* BhiB = Bhi + ((size_t)(n0 + 64 * wc + lrow)) * 256 + lchunk * 8;
    const _Float16* BloB = Blo + ((size_t)(n0 + 64 * wc + lrow)) * 256 + lchunk * 8;

    f32x4 acc0[2][4] = {}, acc1[2][4] = {};

    LOADA(0)
    WRITEA(0)
    __syncthreads();
    LOADA(1)

#pragma unroll
    for (int c = 0; c < 4; ++c) {
        const int buf = c & 1;
#pragma unroll
        for (int ks = 0; ks < 2; ++ks) {
            const int K0 = c * 64 + ks * 32;
            f16x8 ah[2], al[2];
#pragma unroll
            for (int mf = 0; mf < 2; ++mf) {
                unsigned r = (unsigned)(32 * wr + 16 * mf + lrow);
                unsigned off = (r * 128u + (unsigned)(ks * 64 + lchunk * 16)) ^ ((r & 7u) << 4);
                ah[mf] = *(const f16x8*)(Alds + buf * 32768 + off);
                al[mf] = *(const f16x8*)(Alds + buf * 32768 + 16384 + off);
            }
            f16x8 bh[4], bl[4];
#pragma unroll
            for (int nf = 0; nf < 4; ++nf) bh[nf] = *(const f16x8*)(BhiB + nf * 4096 + K0);
#pragma unroll
            for (int nf = 0; nf < 4; ++nf) bl[nf] = *(const f16x8*)(BloB + nf * 4096 + K0);
#pragma unroll
            for (int nf = 0; nf < 4; ++nf)
#pragma unroll
                for (int mf = 0; mf < 2; ++mf)
                    acc0[mf][nf] = __builtin_amdgcn_mfma_f32_16x16x32_f16(ah[mf], bh[nf], acc0[mf][nf], 0, 0, 0);
#pragma unroll
            for (int nf = 0; nf < 4; ++nf)
#pragma unroll
                for (int mf = 0; mf < 2; ++mf)
                    acc1[mf][nf] = __builtin_amdgcn_mfma_f32_16x16x32_f16(ah[mf], bl[nf], acc1[mf][nf], 0, 0, 0);
#pragma unroll
            for (int nf = 0; nf < 4; ++nf)
#pragma unroll
                for (int mf = 0; mf < 2; ++mf)
                    acc1[mf][nf] = __builtin_amdgcn_mfma_f32_16x16x32_f16(al[mf], bh[nf], acc1[mf][nf], 0, 0, 0);
        }
        if (c < 3) {
            __syncthreads();       // all waves done reading buf[(c+1)&1] (chunk c-1)
            WRITEA((c + 1) & 1)    // waits on ld[] loads issued one chunk ago
            if (c < 2) { LOADA(c + 2) }
            __syncthreads();       // staged chunk visible before next compute
        }
    }
#undef LOADA
#undef WRITEA

    // ---- C write (h = acc0 + acc1*2^-12 + bias) + lane-local fp64 column sums ----
    const float UNSCALE = 1.0f / 4096.0f;
    double s[4], q[4];
#pragma unroll
    for (int nf = 0; nf < 4; ++nf) {
        int col = n0 + 64 * wc + 16 * nf + lrow;
        float bvv = bias[col];
        double ss = 0.0, qq = 0.0;
#pragma unroll
        for (int mf = 0; mf < 2; ++mf) {
            size_t rowb = m0 + 32 * wr + 16 * mf + 4 * lchunk;
#pragma unroll
            for (int e = 0; e < 4; ++e) {
                float hv = acc0[mf][nf][e] + acc1[mf][nf][e] * UNSCALE + bvv;
                C[(rowb + e) * 256 + col] = hv;
                ss += (double)hv;
                qq += (double)hv * (double)hv;
            }
        }
        s[nf] = ss;
        q[nf] = qq;
    }
#pragma unroll
    for (int nf = 0; nf < 4; ++nf) {
        s[nf] += __shfl_xor(s[nf], 16);
        s[nf] += __shfl_xor(s[nf], 32);
        q[nf] += __shfl_xor(q[nf], 16);
        q[nf] += __shfl_xor(q[nf], 32);
    }
    __syncthreads();                 // all waves done with Alds
    double* shred = (double*)Alds;   // 8 KB reuse
    if (lane < 16) {
#pragma unroll
        for (int nf = 0; nf < 4; ++nf) {
            shred[(wave * 4 + nf) * 16 + lane] = s[nf];
            shred[512 + (wave * 4 + nf) * 16 + lane] = q[nf];
        }
    }
    __syncthreads();
    if (wave < 2) {  // wave = wc slot; combine wr=0..3 (waves 2*wr+wc)
        int nf = lane >> 4, lr = lane & 15;
        int col_local = 64 * wave + 16 * nf + lr;
        double ssum = 0.0, qsum = 0.0;
#pragma unroll
        for (int w = 0; w < 4; ++w) {
            ssum += shred[((2 * w + wave) * 4 + nf) * 16 + lr];
            qsum += shred[512 + ((2 * w + wave) * 4 + nf) * 16 + lr];
        }
        int c = n0 + col_local;
        partial[(size_t)c * 1024 + bi] = ssum;
        partial[(size_t)(256 + c) * 1024 + bi] = qsum;
    }
}

// ---------------- GEMM2 (MFMA): C = spikes_bf16 @ (Whi+Wmid+Wlo) + bias --------------
// Round-5 config: bb[2][12] full-k0-distance prefetch; A tile 64KB staged once,
// XOR-swizzled; barrier-free K-loop; fused stats (NB=1024).
__global__ __launch_bounds__(512) void gemm2_mfma(const unsigned short* __restrict__ A,
                                                  const unsigned short* __restrict__ Bt,
                                                  const float* __restrict__ bias,
                                                  float* __restrict__ C,
                                                  double* __restrict__ partial) {
    __shared__ __align__(16) unsigned short Asw[128 * 256];  // 64 KB
    const size_t m0 = (size_t)blockIdx.x * 128;
    const int tid = threadIdx.x;
    const int lane = tid & 63;
    const int wave = tid >> 6;   // 0..7
    const int wr = wave >> 2;    // 0..1
    const int wc = wave & 3;     // 0..3
    const int lrow = lane & 15, lchunk = lane >> 4;

    {
        const char* src = (const char*)(A + m0 * 256);
        char* dst = (char*)Asw;
#pragma unroll
        for (int it = 0; it < 8; ++it) {
            unsigned off = (unsigned)(it * 512 + tid) * 16u;
            float4 v = *(const float4*)(src + off);
            unsigned swz = off ^ (((off >> 9) & 7u) << 4);
            *(float4*)(dst + swz) = v;
        }
    }

    const unsigned short* Bbase =
        Bt + ((size_t)(64 * wc + lrow)) * 256 + lchunk * 8;

    bf16x8 bb[2][12];
#define LOADB(buf, kk)                                                        \
    _Pragma("unroll") for (int t = 0; t < 3; ++t)                             \
    _Pragma("unroll") for (int nf = 0; nf < 4; ++nf)                          \
        bb[buf][t * 4 + nf] = *(const bf16x8*)(Bbase + (size_t)t * 65536 +    \
                                               nf * 4096 + (kk) * 32);

    LOADB(0, 0)
    __syncthreads();

    f32x4 acc[4][4] = {};

#pragma unroll
    for (int k0 = 0; k0 < 8; ++k0) {
        const int cur = k0 & 1;
        if (k0 < 7) { LOADB(cur ^ 1, k0 + 1) }
        bf16x8 af[4];
#pragma unroll
        for (int mf = 0; mf < 4; ++mf) {
            unsigned r = (unsigned)(64 * wr + 16 * mf + lrow);
            unsigned off = r * 512u + (unsigned)(k0 * 64 + lchunk * 16);
            off ^= ((r & 7u) << 4);
            af[mf] = *(const bf16x8*)((const char*)Asw + off);
        }
#pragma unroll
        for (int t = 0; t < 3; ++t)
#pragma unroll
            for (int nf = 0; nf < 4; ++nf)
#pragma unroll
                for (int mf = 0; mf < 4; ++mf)
                    acc[mf][nf] = __builtin_amdgcn_mfma_f32_16x16x32_bf16(
                        af[mf], bb[cur][t * 4 + nf], acc[mf][nf], 0, 0, 0);
    }
#undef LOADB

    double s[4], q[4];
#pragma unroll
    for (int nf = 0; nf < 4; ++nf) {
        int col = 64 * wc + 16 * nf + lrow;
        float bvv = bias[col];
        double ss = 0.0, qq = 0.0;
#pragma unroll
        for (int mf = 0; mf < 4; ++mf) {
            size_t rowb = m0 + 64 * wr + 16 * mf + 4 * lchunk;
#pragma unroll
            for (int e = 0; e < 4; ++e) {
                float hv = acc[mf][nf][e] + bvv;
                C[(rowb + e) * 256 + col] = hv;
                ss += (double)hv;
                qq += (double)hv * (double)hv;
            }
        }
        s[nf] = ss;
        q[nf] = qq;
    }
#pragma unroll
    for (int nf = 0; nf < 4; ++nf) {
        s[nf] += __shfl_xor(s[nf], 16);
        s[nf] += __shfl_xor(s[nf], 32);
        q[nf] += __shfl_xor(q[nf], 16);
        q[nf] += __shfl_xor(q[nf], 32);
    }
    __syncthreads();
    double* shred = (double*)Asw;
    if (lane < 16) {
#pragma unroll
        for (int nf = 0; nf < 4; ++nf) {
            shred[(wave * 4 + nf) * 16 + lane] = s[nf];
            shred[512 + (wave * 4 + nf) * 16 + lane] = q[nf];
        }
    }
    __syncthreads();
    if (wave < 4) {
        int nf = lane >> 4, lr = lane & 15;
        int col = 64 * wave + 16 * nf + lr;
        double ssum = shred[(wave * 4 + nf) * 16 + lr] +
                      shred[((4 + wave) * 4 + nf) * 16 + lr];
        double qsum = shred[512 + (wave * 4 + nf) * 16 + lr] +
                      shred[512 + ((4 + wave) * 4 + nf) * 16 + lr];
        partial[(size_t)col * 1024 + blockIdx.x] = ssum;
        partial[(size_t)(256 + col) * 1024 + blockIdx.x] = qsum;
    }
}

// 256 blocks (one per channel) x 256 threads; fixed-order fp64 reduction.
__global__ __launch_bounds__(256) void finalize_stats(const double* __restrict__ partial,
                                                      const float* __restrict__ gamma,
                                                      const float* __restrict__ beta,
                                                      float2* __restrict__ ss,
                                                      int nblocks, double invM) {
    const int c = blockIdx.x;
    const int t = threadIdx.x;
    __shared__ double sh[256];
    __shared__ double sh2[256];
    double s = 0.0, s2 = 0.0;
    for (int b = t; b < nblocks; b += 256) {
        s += partial[(size_t)c * nblocks + b];
        s2 += partial[(size_t)(256 + c) * nblocks + b];
    }
    sh[t] = s;
    sh2[t] = s2;
    __syncthreads();
#pragma unroll
    for (int off = 128; off > 0; off >>= 1) {
        if (t < off) {
            sh[t] += sh[t + off];
            sh2[t] += sh2[t + off];
        }
        __syncthreads();
    }
    if (t == 0) {
        double mu = sh[0] * invM;
        double var = sh2[0] * invM - mu * mu;
        double rstd = 1.0 / sqrt(var + 1e-5);
        double sc = (double)gamma[c] * rstd;
        ss[c] = make_float2((float)sc, (float)((double)beta[c] - mu * sc));
    }
}

// ---------------- Fused BN(affine) + multi-step LIF over T=4 ----------------
__global__ __launch_bounds__(256) void bnlif_bf16(const float* __restrict__ h,
                                                  const float2* __restrict__ ss,
                                                  unsigned short* __restrict__ out,
                                                  int slab4) {
    int t4 = blockIdx.x * 256 + threadIdx.x;
    if (t4 >= slab4) return;
    size_t idx = (size_t)t4 * 4;
    int c0 = (int)(idx & 255);
    float2 p0 = ss[c0], p1 = ss[c0 + 1], p2 = ss[c0 + 2], p3 = ss[c0 + 3];
    size_t slab = (size_t)slab4 * 4;
    float4 v = make_float4(0.f, 0.f, 0.f, 0.f);
#pragma unroll
    for (int t = 0; t < 4; ++t) {
        float4 hv = *(const float4*)(h + (size_t)t * slab + idx);
        float x0 = hv.x * p0.x + p0.y;
        float x1 = hv.y * p1.x + p1.y;
        float x2 = hv.z * p2.x + p2.y;
        float x3 = hv.w * p3.x + p3.y;
        v.x = v.x + (x0 - v.x) * 0.5f;
        v.y = v.y + (x1 - v.y) * 0.5f;
        v.z = v.z + (x2 - v.z) * 0.5f;
        v.w = v.w + (x3 - v.w) * 0.5f;
        ushort4 sp;
        sp.x = (v.x >= 1.0f) ? 0x3F80 : 0;
        sp.y = (v.y >= 1.0f) ? 0x3F80 : 0;
        sp.z = (v.z >= 1.0f) ? 0x3F80 : 0;
        sp.w = (v.w >= 1.0f) ? 0x3F80 : 0;
        v.x = (v.x >= 1.0f) ? 0.0f : v.x;
        v.y = (v.y >= 1.0f) ? 0.0f : v.y;
        v.z = (v.z >= 1.0f) ? 0.0f : v.z;
        v.w = (v.w >= 1.0f) ? 0.0f : v.w;
        *(ushort4*)(out + (size_t)t * slab + idx) = sp;
    }
}

__global__ __launch_bounds__(256) void bnlif_f32(const float* __restrict__ h,
                                                 const float2* __restrict__ ss,
                                                 float* __restrict__ out,
                                                 int slab4) {
    int t4 = blockIdx.x * 256 + threadIdx.x;
    if (t4 >= slab4) return;
    size_t idx = (size_t)t4 * 4;
    int c0 = (int)(idx & 255);
    float2 p0 = ss[c0], p1 = ss[c0 + 1], p2 = ss[c0 + 2], p3 = ss[c0 + 3];
    size_t slab = (size_t)slab4 * 4;
    float4 v = make_float4(0.f, 0.f, 0.f, 0.f);
#pragma unroll
    for (int t = 0; t < 4; ++t) {
        float4 hv = *(const float4*)(h + (size_t)t * slab + idx);
        float x0 = hv.x * p0.x + p0.y;
        float x1 = hv.y * p1.x + p1.y;
        float x2 = hv.z * p2.x + p2.y;
        float x3 = hv.w * p3.x + p3.y;
        v.x = v.x + (x0 - v.x) * 0.5f;
        v.y = v.y + (x1 - v.y) * 0.5f;
        v.z = v.z + (x2 - v.z) * 0.5f;
        v.w = v.w + (x3 - v.w) * 0.5f;
        float4 sp;
        sp.x = (v.x >= 1.0f) ? 1.0f : 0.0f;
        sp.y = (v.y >= 1.0f) ? 1.0f : 0.0f;
        sp.z = (v.z >= 1.0f) ? 1.0f : 0.0f;
        sp.w = (v.w >= 1.0f) ? 1.0f : 0.0f;
        v.x = (v.x >= 1.0f) ? 0.0f : v.x;
        v.y = (v.y >= 1.0f) ? 0.0f : v.y;
        v.z = (v.z >= 1.0f) ? 0.0f : v.z;
        v.w = (v.w >= 1.0f) ? 0.0f : v.w;
        *(float4*)(out + (size_t)t * slab + idx) = sp;
    }
}

extern "C" void kernel_launch(void* const* d_in, const int* in_sizes, int n_in,
                              void* d_out, int out_size, void* d_ws, size_t ws_size,
                              hipStream_t stream) {
    const float* x  = (const float*)d_in[0];
    const float* W1 = (const float*)d_in[1];
    const float* b1 = (const float*)d_in[2];
    const float* g1 = (const float*)d_in[3];
    const float* be1 = (const float*)d_in[4];
    const float* W2 = (const float*)d_in[5];
    const float* b2 = (const float*)d_in[6];
    const float* g2 = (const float*)d_in[7];
    const float* be2 = (const float*)d_in[8];
    float* out = (float*)d_out;

    const int M = in_sizes[0] / 256;            // 131072
    const size_t hBytes = (size_t)M * 256 * 4;  // 128 MiB

    char* ws = (char*)d_ws;
    float* h = (float*)ws;                                   // 128 MiB fp32 (h / o)
    unsigned short* s1b = (unsigned short*)(ws + hBytes);    // 64 MiB bf16 spikes
    double* partial = (double*)(ws + hBytes + hBytes / 2);   // 4 MiB (shared, sequential)
    const int NB = 1024;
    unsigned short* W2catT = (unsigned short*)(ws + hBytes + hBytes / 2 + (size_t)NB * 512 * 8);
    float2* ss1 = (float2*)((char*)W2catT + 3 * 256 * 256 * 2);
    float2* ss2 = ss1 + 256;
    _Float16* W1hiT = (_Float16*)(ss2 + 256);
    _Float16* W1loT = W1hiT + 256 * 256;

    const int slab4 = M * 16;
    const double invM = 1.0 / (double)M;

    dim3 blk(256);

    // weight splits
    split_w1<<<dim3(256), blk, 0, stream>>>(W1, W1hiT, W1loT);
    split_w2<<<dim3(256), blk, 0, stream>>>(W2, W2catT);

    // ---- layer 1 (fp16x2-split MFMA GEMM, K-pipelined, 2 blocks/CU + fused stats) ----
    gemm1_mfma<<<dim3((M / 128) * 2), dim3(512), 0, stream>>>(x, W1hiT, W1loT, b1, h, partial);
    finalize_stats<<<dim3(256), blk, 0, stream>>>(partial, g1, be1, ss1, NB, invM);
    bnlif_bf16<<<dim3(slab4 / 256), blk, 0, stream>>>(h, ss1, s1b, slab4);

    // ---- layer 2 (bf16x3 MFMA GEMM, exact; reg-dbuf B; fused stats) ----
    gemm2_mfma<<<dim3(M / 128), dim3(512), 0, stream>>>(s1b, W2catT, b2, h, partial);
    finalize_stats<<<dim3(256), blk, 0, stream>>>(partial, g2, be2, ss2, NB, invM);
    bnlif_f32<<<dim3(slab4 / 256), blk, 0, stream>>>(h, ss2, out, slab4);
}

// Round 10
// 396.153 us; speedup vs baseline: 1.3341x; 1.3341x over previous
//
#include <hip/hip_runtime.h>

// x[T=4,B=32,N=1024,C=256] -> Linear -> BN -> LIF -> Linear -> BN -> LIF
// M = 131072 rows, fp32 in/out.
// GEMM2: spikes 0/1 (exact bf16) @ exact 3-term bf16 split of W2 (MFMA), r5 config.
// GEMM1 v4 (round 10): fp16 2-term split, 3 products; BM=64 x full N=256, LDS 64KB,
// ~128 VGPR, launch_bounds(512,4) -> 2 blocks/CU for phase overlap. A read once,
// full-row writes (r9 lesson: n-splitting quadruples HBM traffic).

typedef __attribute__((ext_vector_type(8))) short bf16x8;
typedef __attribute__((ext_vector_type(8))) _Float16 f16x8;
typedef __attribute__((ext_vector_type(4))) _Float16 f16x4;
typedef __attribute__((ext_vector_type(4))) float f32x4;

__device__ __forceinline__ unsigned short f32_to_bf16_rne(float f) {
    unsigned int u = __builtin_bit_cast(unsigned int, f);
    u += 0x7FFFu + ((u >> 16) & 1u);
    return (unsigned short)(u >> 16);
}
__device__ __forceinline__ float bf16_to_f32(unsigned short h) {
    unsigned int u = ((unsigned int)h) << 16;
    return __builtin_bit_cast(float, u);
}

// -------- W1 split: W1[k][n] fp32 -> W1hiT/W1loT[n][k] fp16 (lo pre-scaled 2^12) -----
__global__ __launch_bounds__(256) void split_w1(const float* __restrict__ W1,
                                                _Float16* __restrict__ BhiT,
                                                _Float16* __restrict__ BloT) {
    int i = blockIdx.x * 256 + threadIdx.x;  // 65536
    int k = i >> 8, n = i & 255;
    float w = W1[i];
    _Float16 hi = (_Float16)w;
    _Float16 lo = (_Float16)((w - (float)hi) * 4096.0f);
    BhiT[(size_t)n * 256 + k] = hi;
    BloT[(size_t)n * 256 + k] = lo;
}

// -------- W2 split: W2[k][n] fp32 -> W2catT[t][n][k] bf16, t=hi/mid/lo (exact sum) ----
__global__ __launch_bounds__(256) void split_w2(const float* __restrict__ W2,
                                                unsigned short* __restrict__ Bt) {
    int i = blockIdx.x * 256 + threadIdx.x;  // 65536
    int k = i >> 8, n = i & 255;
    float w = W2[i];
    unsigned short hi = f32_to_bf16_rne(w);
    float r = w - bf16_to_f32(hi);
    unsigned short mid = f32_to_bf16_rne(r);
    float r2 = r - bf16_to_f32(mid);
    unsigned short lo = f32_to_bf16_rne(r2);
    Bt[(size_t)(0 * 256 + n) * 256 + k] = hi;
    Bt[(size_t)(1 * 256 + n) * 256 + k] = mid;
    Bt[(size_t)(2 * 256 + n) * 256 + k] = lo;
}

// ---------------- GEMM1 v4 (MFMA, fp16 2-split x 3 products), BM=64 ------------------
// 2048 blocks x 64 rows, full 256 cols. 8 waves: wr=wave>>2 (32-row), wc=wave&3
// (64-col); wave tile 32x64, acc (2mf x 4nf) x 2. B single-buffered (TLP hides L2).
__global__ __launch_bounds__(512, 4) void gemm1_mfma(const float* __restrict__ A,
                                                     const _Float16* __restrict__ Bhi,
                                                     const _Float16* __restrict__ Blo,
                                                     const float* __restrict__ bias,
                                                     float* __restrict__ C,
                                                     double* __restrict__ partial) {
    __shared__ __align__(16) _Float16 Ahi[64 * 256];  // 32 KB
    __shared__ __align__(16) _Float16 Alo[64 * 256];  // 32 KB
    const size_t m0 = (size_t)blockIdx.x * 64;
    const int tid = threadIdx.x;
    const int lane = tid & 63;
    const int wave = tid >> 6;   // 0..7
    const int wr = wave >> 2;    // 0..1 (32-row group)
    const int wc = wave & 3;     // 0..3 (64-col group)
    const int lrow = lane & 15, lchunk = lane >> 4;

    // ---- stage A tile: 64 rows x 256 cols fp32 -> (hi, lo*4096) fp16 LDS, swizzled --
    {
        const float* src = A + m0 * 256;
#pragma unroll
        for (int it = 0; it < 8; ++it) {
            unsigned i4 = (unsigned)(it * 512 + tid);   // float4 index, 4096 total
            float4 v = *(const float4*)(src + (size_t)i4 * 4);
            float f[4] = {v.x, v.y, v.z, v.w};
            f16x4 hi4, lo4;
#pragma unroll
            for (int e = 0; e < 4; ++e) {
                _Float16 hh = (_Float16)f[e];
                hi4[e] = hh;
                lo4[e] = (_Float16)((f[e] - (float)hh) * 4096.0f);
            }
            unsigned row = i4 >> 6;                     // 64 float4 per row
            unsigned colq = i4 & 63;
            unsigned off = (row * 512u + colq * 8u) ^ ((row & 7u) << 4);
            *(f16x4*)((char*)Ahi + off) = hi4;
            *(f16x4*)((char*)Alo + off) = lo4;
        }
    }
    __syncthreads();

    const _Float16* BhiB = Bhi + ((size_t)(64 * wc + lrow)) * 256 + lchunk * 8;
    const _Float16* BloB = Blo + ((size_t)(64 * wc + lrow)) * 256 + lchunk * 8;

    f32x4 acc0[2][4] = {}, acc1[2][4] = {};

#pragma unroll
    for (int k0 = 0; k0 < 8; ++k0) {
        f16x8 bh[4], bl[4];
#pragma unroll
        for (int nf = 0; nf < 4; ++nf) bh[nf] = *(const f16x8*)(BhiB + nf * 4096 + k0 * 32);
#pragma unroll
        for (int nf = 0; nf < 4; ++nf) bl[nf] = *(const f16x8*)(BloB + nf * 4096 + k0 * 32);
        f16x8 ah[2], al[2];
#pragma unroll
        for (int mf = 0; mf < 2; ++mf) {
            unsigned r = (unsigned)(32 * wr + 16 * mf + lrow);
            unsigned off = (r * 512u + (unsigned)(k0 * 64 + lchunk * 16)) ^ ((r & 7u) << 4);
            ah[mf] = *(const f16x8*)((const char*)Ahi + off);
            al[mf] = *(const f16x8*)((const char*)Alo + off);
        }
#pragma unroll
        for (int nf = 0; nf < 4; ++nf)
#pragma unroll
            for (int mf = 0; mf < 2; ++mf)
                acc0[mf][nf] = __builtin_amdgcn_mfma_f32_16x16x32_f16(ah[mf], bh[nf], acc0[mf][nf], 0, 0, 0);
#pragma unroll
        for (int nf = 0; nf < 4; ++nf)
#pragma unroll
            for (int mf = 0; mf < 2; ++mf)
                acc1[mf][nf] = __builtin_amdgcn_mfma_f32_16x16x32_f16(ah[mf], bl[nf], acc1[mf][nf], 0, 0, 0);
#pragma unroll
        for (int nf = 0; nf < 4; ++nf)
#pragma unroll
            for (int mf = 0; mf < 2; ++mf)
                acc1[mf][nf] = __builtin_amdgcn_mfma_f32_16x16x32_f16(al[mf], bh[nf], acc1[mf][nf], 0, 0, 0);
    }

    // ---- C write (h = acc0 + acc1*2^-12 + bias) + lane-local fp64 column sums ----
    const float UNSCALE = 1.0f / 4096.0f;
    double s[4], q[4];
#pragma unroll
    for (int nf = 0; nf < 4; ++nf) {
        int col = 64 * wc + 16 * nf + lrow;
        float bvv = bias[col];
        double ss = 0.0, qq = 0.0;
#pragma unroll
        for (int mf = 0; mf < 2; ++mf) {
            size_t rowb = m0 + 32 * wr + 16 * mf + 4 * lchunk;
#pragma unroll
            for (int e = 0; e < 4; ++e) {
                float hv = acc0[mf][nf][e] + acc1[mf][nf][e] * UNSCALE + bvv;
                C[(rowb + e) * 256 + col] = hv;
                ss += (double)hv;
                qq += (double)hv * (double)hv;
            }
        }
        s[nf] = ss;
        q[nf] = qq;
    }
#pragma unroll
    for (int nf = 0; nf < 4; ++nf) {
        s[nf] += __shfl_xor(s[nf], 16);
        s[nf] += __shfl_xor(s[nf], 32);
        q[nf] += __shfl_xor(q[nf], 16);
        q[nf] += __shfl_xor(q[nf], 32);
    }
    __syncthreads();                 // all waves done with Ahi/Alo
    double* shred = (double*)Ahi;    // 8 KB reuse
    if (lane < 16) {
#pragma unroll
        for (int nf = 0; nf < 4; ++nf) {
            shred[(wave * 4 + nf) * 16 + lane] = s[nf];
            shred[512 + (wave * 4 + nf) * 16 + lane] = q[nf];
        }
    }
    __syncthreads();
    if (wave < 4) {  // combine wr=0 (waves 0-3) and wr=1 (waves 4-7), wave = wc slot
        int nf = lane >> 4, lr = lane & 15;
        int col = 64 * wave + 16 * nf + lr;
        double ssum = shred[(wave * 4 + nf) * 16 + lr] +
                      shred[((4 + wave) * 4 + nf) * 16 + lr];
        double qsum = shred[512 + (wave * 4 + nf) * 16 + lr] +
                      shred[512 + ((4 + wave) * 4 + nf) * 16 + lr];
        partial[(size_t)col * 2048 + blockIdx.x] = ssum;
        partial[(size_t)(256 + col) * 2048 + blockIdx.x] = qsum;
    }
}

// ---------------- GEMM2 (MFMA): C = spikes_bf16 @ (Whi+Wmid+Wlo) + bias --------------
// Round-5 config: bb[2][12] full-k0-distance prefetch; A tile 64KB staged once,
// XOR-swizzled; barrier-free K-loop; fused stats (NB=1024).
__global__ __launch_bounds__(512) void gemm2_mfma(const unsigned short* __restrict__ A,
                                                  const unsigned short* __restrict__ Bt,
                                                  const float* __restrict__ bias,
                                                  float* __restrict__ C,
                                                  double* __restrict__ partial) {
    __shared__ __align__(16) unsigned short Asw[128 * 256];  // 64 KB
    const size_t m0 = (size_t)blockIdx.x * 128;
    const int tid = threadIdx.x;
    const int lane = tid & 63;
    const int wave = tid >> 6;   // 0..7
    const int wr = wave >> 2;    // 0..1
    const int wc = wave & 3;     // 0..3
    const int lrow = lane & 15, lchunk = lane >> 4;

    {
        const char* src = (const char*)(A + m0 * 256);
        char* dst = (char*)Asw;
#pragma unroll
        for (int it = 0; it < 8; ++it) {
            unsigned off = (unsigned)(it * 512 + tid) * 16u;
            float4 v = *(const float4*)(src + off);
            unsigned swz = off ^ (((off >> 9) & 7u) << 4);
            *(float4*)(dst + swz) = v;
        }
    }

    const unsigned short* Bbase =
        Bt + ((size_t)(64 * wc + lrow)) * 256 + lchunk * 8;

    bf16x8 bb[2][12];
#define LOADB(buf, kk)                                                        \
    _Pragma("unroll") for (int t = 0; t < 3; ++t)                             \
    _Pragma("unroll") for (int nf = 0; nf < 4; ++nf)                          \
        bb[buf][t * 4 + nf] = *(const bf16x8*)(Bbase + (size_t)t * 65536 +    \
                                               nf * 4096 + (kk) * 32);

    LOADB(0, 0)
    __syncthreads();

    f32x4 acc[4][4] = {};

#pragma unroll
    for (int k0 = 0; k0 < 8; ++k0) {
        const int cur = k0 & 1;
        if (k0 < 7) { LOADB(cur ^ 1, k0 + 1) }
        bf16x8 af[4];
#pragma unroll
        for (int mf = 0; mf < 4; ++mf) {
            unsigned r = (unsigned)(64 * wr + 16 * mf + lrow);
            unsigned off = r * 512u + (unsigned)(k0 * 64 + lchunk * 16);
            off ^= ((r & 7u) << 4);
            af[mf] = *(const bf16x8*)((const char*)Asw + off);
        }
#pragma unroll
        for (int t = 0; t < 3; ++t)
#pragma unroll
            for (int nf = 0; nf < 4; ++nf)
#pragma unroll
                for (int mf = 0; mf < 4; ++mf)
                    acc[mf][nf] = __builtin_amdgcn_mfma_f32_16x16x32_bf16(
                        af[mf], bb[cur][t * 4 + nf], acc[mf][nf], 0, 0, 0);
    }
#undef LOADB

    double s[4], q[4];
#pragma unroll
    for (int nf = 0; nf < 4; ++nf) {
        int col = 64 * wc + 16 * nf + lrow;
        float bvv = bias[col];
        double ss = 0.0, qq = 0.0;
#pragma unroll
        for (int mf = 0; mf < 4; ++mf) {
            size_t rowb = m0 + 64 * wr + 16 * mf + 4 * lchunk;
#pragma unroll
            for (int e = 0; e < 4; ++e) {
                float hv = acc[mf][nf][e] + bvv;
                C[(rowb + e) * 256 + col] = hv;
                ss += (double)hv;
                qq += (double)hv * (double)hv;
            }
        }
        s[nf] = ss;
        q[nf] = qq;
    }
#pragma unroll
    for (int nf = 0; nf < 4; ++nf) {
        s[nf] += __shfl_xor(s[nf], 16);
        s[nf] += __shfl_xor(s[nf], 32);
        q[nf] += __shfl_xor(q[nf], 16);
        q[nf] += __shfl_xor(q[nf], 32);
    }
    __syncthreads();
    double* shred = (double*)Asw;
    if (lane < 16) {
#pragma unroll
        for (int nf = 0; nf < 4; ++nf) {
            shred[(wave * 4 + nf) * 16 + lane] = s[nf];
            shred[512 + (wave * 4 + nf) * 16 + lane] = q[nf];
        }
    }
    __syncthreads();
    if (wave < 4) {
        int nf = lane >> 4, lr = lane & 15;
        int col = 64 * wave + 16 * nf + lr;
        double ssum = shred[(wave * 4 + nf) * 16 + lr] +
                      shred[((4 + wave) * 4 + nf) * 16 + lr];
        double qsum = shred[512 + (wave * 4 + nf) * 16 + lr] +
                      shred[512 + ((4 + wave) * 4 + nf) * 16 + lr];
        partial[(size_t)col * 1024 + blockIdx.x] = ssum;
        partial[(size_t)(256 + col) * 1024 + blockIdx.x] = qsum;
    }
}

// 256 blocks (one per channel) x 256 threads; fixed-order fp64 reduction.
__global__ __launch_bounds__(256) void finalize_stats(const double* __restrict__ partial,
                                                      const float* __restrict__ gamma,
                                                      const float* __restrict__ beta,
                                                      float2* __restrict__ ss,
                                                      int nblocks, double invM) {
    const int c = blockIdx.x;
    const int t = threadIdx.x;
    __shared__ double sh[256];
    __shared__ double sh2[256];
    double s = 0.0, s2 = 0.0;
    for (int b = t; b < nblocks; b += 256) {
        s += partial[(size_t)c * nblocks + b];
        s2 += partial[(size_t)(256 + c) * nblocks + b];
    }
    sh[t] = s;
    sh2[t] = s2;
    __syncthreads();
#pragma unroll
    for (int off = 128; off > 0; off >>= 1) {
        if (t < off) {
            sh[t] += sh[t + off];
            sh2[t] += sh2[t + off];
        }
        __syncthreads();
    }
    if (t == 0) {
        double mu = sh[0] * invM;
        double var = sh2[0] * invM - mu * mu;
        double rstd = 1.0 / sqrt(var + 1e-5);
        double sc = (double)gamma[c] * rstd;
        ss[c] = make_float2((float)sc, (float)((double)beta[c] - mu * sc));
    }
}

// ---------------- Fused BN(affine) + multi-step LIF over T=4 ----------------
__global__ __launch_bounds__(256) void bnlif_bf16(const float* __restrict__ h,
                                                  const float2* __restrict__ ss,
                                                  unsigned short* __restrict__ out,
                                                  int slab4) {
    int t4 = blockIdx.x * 256 + threadIdx.x;
    if (t4 >= slab4) return;
    size_t idx = (size_t)t4 * 4;
    int c0 = (int)(idx & 255);
    float2 p0 = ss[c0], p1 = ss[c0 + 1], p2 = ss[c0 + 2], p3 = ss[c0 + 3];
    size_t slab = (size_t)slab4 * 4;
    float4 v = make_float4(0.f, 0.f, 0.f, 0.f);
#pragma unroll
    for (int t = 0; t < 4; ++t) {
        float4 hv = *(const float4*)(h + (size_t)t * slab + idx);
        float x0 = hv.x * p0.x + p0.y;
        float x1 = hv.y * p1.x + p1.y;
        float x2 = hv.z * p2.x + p2.y;
        float x3 = hv.w * p3.x + p3.y;
        v.x = v.x + (x0 - v.x) * 0.5f;
        v.y = v.y + (x1 - v.y) * 0.5f;
        v.z = v.z + (x2 - v.z) * 0.5f;
        v.w = v.w + (x3 - v.w) * 0.5f;
        ushort4 sp;
        sp.x = (v.x >= 1.0f) ? 0x3F80 : 0;
        sp.y = (v.y >= 1.0f) ? 0x3F80 : 0;
        sp.z = (v.z >= 1.0f) ? 0x3F80 : 0;
        sp.w = (v.w >= 1.0f) ? 0x3F80 : 0;
        v.x = (v.x >= 1.0f) ? 0.0f : v.x;
        v.y = (v.y >= 1.0f) ? 0.0f : v.y;
        v.z = (v.z >= 1.0f) ? 0.0f : v.z;
        v.w = (v.w >= 1.0f) ? 0.0f : v.w;
        *(ushort4*)(out + (size_t)t * slab + idx) = sp;
    }
}

__global__ __launch_bounds__(256) void bnlif_f32(const float* __restrict__ h,
                                                 const float2* __restrict__ ss,
                                                 float* __restrict__ out,
                                                 int slab4) {
    int t4 = blockIdx.x * 256 + threadIdx.x;
    if (t4 >= slab4) return;
    size_t idx = (size_t)t4 * 4;
    int c0 = (int)(idx & 255);
    float2 p0 = ss[c0], p1 = ss[c0 + 1], p2 = ss[c0 + 2], p3 = ss[c0 + 3];
    size_t slab = (size_t)slab4 * 4;
    float4 v = make_float4(0.f, 0.f, 0.f, 0.f);
#pragma unroll
    for (int t = 0; t < 4; ++t) {
        float4 hv = *(const float4*)(h + (size_t)t * slab + idx);
        float x0 = hv.x * p0.x + p0.y;
        float x1 = hv.y * p1.x + p1.y;
        float x2 = hv.z * p2.x + p2.y;
        float x3 = hv.w * p3.x + p3.y;
        v.x = v.x + (x0 - v.x) * 0.5f;
        v.y = v.y + (x1 - v.y) * 0.5f;
        v.z = v.z + (x2 - v.z) * 0.5f;
        v.w = v.w + (x3 - v.w) * 0.5f;
        float4 sp;
        sp.x = (v.x >= 1.0f) ? 1.0f : 0.0f;
        sp.y = (v.y >= 1.0f) ? 1.0f : 0.0f;
        sp.z = (v.z >= 1.0f) ? 1.0f : 0.0f;
        sp.w = (v.w >= 1.0f) ? 1.0f : 0.0f;
        v.x = (v.x >= 1.0f) ? 0.0f : v.x;
        v.y = (v.y >= 1.0f) ? 0.0f : v.y;
        v.z = (v.z >= 1.0f) ? 0.0f : v.z;
        v.w = (v.w >= 1.0f) ? 0.0f : v.w;
        *(float4*)(out + (size_t)t * slab + idx) = sp;
    }
}

extern "C" void kernel_launch(void* const* d_in, const int* in_sizes, int n_in,
                              void* d_out, int out_size, void* d_ws, size_t ws_size,
                              hipStream_t stream) {
    const float* x  = (const float*)d_in[0];
    const float* W1 = (const float*)d_in[1];
    const float* b1 = (const float*)d_in[2];
    const float* g1 = (const float*)d_in[3];
    const float* be1 = (const float*)d_in[4];
    const float* W2 = (const float*)d_in[5];
    const float* b2 = (const float*)d_in[6];
    const float* g2 = (const float*)d_in[7];
    const float* be2 = (const float*)d_in[8];
    float* out = (float*)d_out;

    const int M = in_sizes[0] / 256;            // 131072
    const size_t hBytes = (size_t)M * 256 * 4;  // 128 MiB

    char* ws = (char*)d_ws;
    float* h = (float*)ws;                                   // 128 MiB fp32 (h / o)
    unsigned short* s1b = (unsigned short*)(ws + hBytes);    // 64 MiB bf16 spikes
    // partial1 (gemm1, NB=2048, 8.4 MiB) ALIASES s1b: fully consumed by
    // finalize_stats(layer1) before bnlif_bf16 writes s1b (stream-ordered).
    double* partial1 = (double*)(ws + hBytes);
    double* partial2 = (double*)(ws + hBytes + hBytes / 2);  // 4 MiB
    unsigned short* W2catT = (unsigned short*)(ws + hBytes + hBytes / 2 + (size_t)1024 * 512 * 8);
    float2* ss1 = (float2*)((char*)W2catT + 3 * 256 * 256 * 2);
    float2* ss2 = ss1 + 256;
    _Float16* W1hiT = (_Float16*)(ss2 + 256);
    _Float16* W1loT = W1hiT + 256 * 256;

    const int slab4 = M * 16;
    const double invM = 1.0 / (double)M;

    dim3 blk(256);

    // weight splits
    split_w1<<<dim3(256), blk, 0, stream>>>(W1, W1hiT, W1loT);
    split_w2<<<dim3(256), blk, 0, stream>>>(W2, W2catT);

    // ---- layer 1 (fp16x2-split MFMA GEMM, BM=64, 2 blocks/CU + fused stats NB=2048) --
    gemm1_mfma<<<dim3(M / 64), dim3(512), 0, stream>>>(x, W1hiT, W1loT, b1, h, partial1);
    finalize_stats<<<dim3(256), blk, 0, stream>>>(partial1, g1, be1, ss1, 2048, invM);
    bnlif_bf16<<<dim3(slab4 / 256), blk, 0, stream>>>(h, ss1, s1b, slab4);

    // ---- layer 2 (bf16x3 MFMA GEMM, exact; reg-dbuf B; fused stats NB=1024) ----
    gemm2_mfma<<<dim3(M / 128), dim3(512), 0, stream>>>(s1b, W2catT, b2, h, partial2);
    finalize_stats<<<dim3(256), blk, 0, stream>>>(partial2, g2, be2, ss2, 1024, invM);
    bnlif_f32<<<dim3(slab4 / 256), blk, 0, stream>>>(h, ss2, out, slab4);
}

// Round 11
// 329.367 us; speedup vs baseline: 1.6046x; 1.2028x over previous
//
#include <hip/hip_runtime.h>

// x[T=4,B=32,N=1024,C=256] -> Linear -> BN -> LIF -> Linear -> BN -> LIF
// M = 131072 rows, fp32 in/out.
// GEMM1 (r7 config): fp16 2-term split of x and W1, 3 products, BM=128, ratio 6.
// GEMM2 (round 11): BN(ss1)+LIF fused into staging (reads h fp32 directly; block
//   covers 4 timesteps x 32 bn-rows so the LIF t-chain is thread-local), then
//   spikes_bf16 @ exact 3-term bf16 split of W2, r5 K-loop.
// Partial stats layout [block][channel]: contiguous 4KB writes per block.

typedef __attribute__((ext_vector_type(8))) short bf16x8;
typedef __attribute__((ext_vector_type(8))) _Float16 f16x8;
typedef __attribute__((ext_vector_type(4))) _Float16 f16x4;
typedef __attribute__((ext_vector_type(4))) float f32x4;

__device__ __forceinline__ unsigned short f32_to_bf16_rne(float f) {
    unsigned int u = __builtin_bit_cast(unsigned int, f);
    u += 0x7FFFu + ((u >> 16) & 1u);
    return (unsigned short)(u >> 16);
}
__device__ __forceinline__ float bf16_to_f32(unsigned short h) {
    unsigned int u = ((unsigned int)h) << 16;
    return __builtin_bit_cast(float, u);
}

// -------- W1 split: W1[k][n] fp32 -> W1hiT/W1loT[n][k] fp16 (lo pre-scaled 2^12) -----
__global__ __launch_bounds__(256) void split_w1(const float* __restrict__ W1,
                                                _Float16* __restrict__ BhiT,
                                                _Float16* __restrict__ BloT) {
    int i = blockIdx.x * 256 + threadIdx.x;  // 65536
    int k = i >> 8, n = i & 255;
    float w = W1[i];
    _Float16 hi = (_Float16)w;
    _Float16 lo = (_Float16)((w - (float)hi) * 4096.0f);
    BhiT[(size_t)n * 256 + k] = hi;
    BloT[(size_t)n * 256 + k] = lo;
}

// -------- W2 split: W2[k][n] fp32 -> W2catT[t][n][k] bf16, t=hi/mid/lo (exact sum) ----
__global__ __launch_bounds__(256) void split_w2(const float* __restrict__ W2,
                                                unsigned short* __restrict__ Bt) {
    int i = blockIdx.x * 256 + threadIdx.x;  // 65536
    int k = i >> 8, n = i & 255;
    float w = W2[i];
    unsigned short hi = f32_to_bf16_rne(w);
    float r = w - bf16_to_f32(hi);
    unsigned short mid = f32_to_bf16_rne(r);
    float r2 = r - bf16_to_f32(mid);
    unsigned short lo = f32_to_bf16_rne(r2);
    Bt[(size_t)(0 * 256 + n) * 256 + k] = hi;
    Bt[(size_t)(1 * 256 + n) * 256 + k] = mid;
    Bt[(size_t)(2 * 256 + n) * 256 + k] = lo;
}

// ---------------- GEMM1 (MFMA, fp16 2-split x 3 products), BM=128 (r7 config) --------
__global__ __launch_bounds__(512) void gemm1_mfma(const float* __restrict__ A,
                                                  const _Float16* __restrict__ Bhi,
                                                  const _Float16* __restrict__ Blo,
                                                  const float* __restrict__ bias,
                                                  float* __restrict__ C,
                                                  double* __restrict__ partial) {
    __shared__ __align__(16) _Float16 Ahi[128 * 256];  // 64 KB
    __shared__ __align__(16) _Float16 Alo[128 * 256];  // 64 KB
    const size_t m0 = (size_t)blockIdx.x * 128;
    const int tid = threadIdx.x;
    const int lane = tid & 63;
    const int wave = tid >> 6;   // 0..7
    const int wr = wave >> 2;    // 0..1
    const int wc = wave & 3;     // 0..3
    const int lrow = lane & 15, lchunk = lane >> 4;

    const _Float16* BhiB = Bhi + ((size_t)(64 * wc + lrow)) * 256 + lchunk * 8;
    const _Float16* BloB = Blo + ((size_t)(64 * wc + lrow)) * 256 + lchunk * 8;

    f16x8 bh[2][4], bl[2][4];
#define LOADB1(buf, kk)                                                   \
    _Pragma("unroll") for (int nf = 0; nf < 4; ++nf) {                    \
        bh[buf][nf] = *(const f16x8*)(BhiB + nf * 4096 + (kk) * 32);      \
        bl[buf][nf] = *(const f16x8*)(BloB + nf * 4096 + (kk) * 32);      \
    }

    LOADB1(0, 0)  // in flight during staging

    // ---- stage A tile: fp32 global -> (hi, lo*4096) fp16 LDS, swizzled ----
    {
        const float* src = A + m0 * 256;
#pragma unroll
        for (int it = 0; it < 16; ++it) {
            unsigned i4 = (unsigned)(it * 512 + tid);   // float4 index, 8192 total
            float4 v = *(const float4*)(src + (size_t)i4 * 4);
            float f[4] = {v.x, v.y, v.z, v.w};
            f16x4 hi4, lo4;
#pragma unroll
            for (int e = 0; e < 4; ++e) {
                _Float16 hh = (_Float16)f[e];
                hi4[e] = hh;
                lo4[e] = (_Float16)((f[e] - (float)hh) * 4096.0f);
            }
            unsigned off = i4 * 8u;                     // byte offset in f16 tile
            unsigned swz = off ^ (((off >> 9) & 7u) << 4);
            *(f16x4*)((char*)Ahi + swz) = hi4;
            *(f16x4*)((char*)Alo + swz) = lo4;
        }
    }
    __syncthreads();

    f32x4 acc0[4][4] = {}, acc1[4][4] = {};

#pragma unroll
    for (int k0 = 0; k0 < 8; ++k0) {
        const int cur = k0 & 1;
        if (k0 < 7) { LOADB1(cur ^ 1, k0 + 1) }
        f16x8 ah[4], al[4];
#pragma unroll
        for (int mf = 0; mf < 4; ++mf) {
            unsigned r = (unsigned)(64 * wr + 16 * mf + lrow);
            unsigned off = (r * 512u + (unsigned)(k0 * 64 + lchunk * 16)) ^ ((r & 7u) << 4);
            ah[mf] = *(const f16x8*)((const char*)Ahi + off);
            al[mf] = *(const f16x8*)((const char*)Alo + off);
        }
#pragma unroll
        for (int nf = 0; nf < 4; ++nf)
#pragma unroll
            for (int mf = 0; mf < 4; ++mf)
                acc0[mf][nf] = __builtin_amdgcn_mfma_f32_16x16x32_f16(
                    ah[mf], bh[cur][nf], acc0[mf][nf], 0, 0, 0);
#pragma unroll
        for (int nf = 0; nf < 4; ++nf)
#pragma unroll
            for (int mf = 0; mf < 4; ++mf)
                acc1[mf][nf] = __builtin_amdgcn_mfma_f32_16x16x32_f16(
                    ah[mf], bl[cur][nf], acc1[mf][nf], 0, 0, 0);
#pragma unroll
        for (int nf = 0; nf < 4; ++nf)
#pragma unroll
            for (int mf = 0; mf < 4; ++mf)
                acc1[mf][nf] = __builtin_amdgcn_mfma_f32_16x16x32_f16(
                    al[mf], bh[cur][nf], acc1[mf][nf], 0, 0, 0);
    }
#undef LOADB1

    // ---- C write (h = acc0 + acc1*2^-12 + bias) + lane-local fp64 column sums ----
    const float UNSCALE = 1.0f / 4096.0f;
    double s[4], q[4];
#pragma unroll
    for (int nf = 0; nf < 4; ++nf) {
        int col = 64 * wc + 16 * nf + lrow;
        float bvv = bias[col];
        double ss = 0.0, qq = 0.0;
#pragma unroll
        for (int mf = 0; mf < 4; ++mf) {
            size_t rowb = m0 + 64 * wr + 16 * mf + 4 * lchunk;
#pragma unroll
            for (int e = 0; e < 4; ++e) {
                float hv = acc0[mf][nf][e] + acc1[mf][nf][e] * UNSCALE + bvv;
                C[(rowb + e) * 256 + col] = hv;
                ss += (double)hv;
                qq += (double)hv * (double)hv;
            }
        }
        s[nf] = ss;
        q[nf] = qq;
    }
#pragma unroll
    for (int nf = 0; nf < 4; ++nf) {
        s[nf] += __shfl_xor(s[nf], 16);
        s[nf] += __shfl_xor(s[nf], 32);
        q[nf] += __shfl_xor(q[nf], 16);
        q[nf] += __shfl_xor(q[nf], 32);
    }
    __syncthreads();
    double* shred = (double*)Ahi;
    if (lane < 16) {
#pragma unroll
        for (int nf = 0; nf < 4; ++nf) {
            shred[(wave * 4 + nf) * 16 + lane] = s[nf];
            shred[512 + (wave * 4 + nf) * 16 + lane] = q[nf];
        }
    }
    __syncthreads();
    if (wave < 4) {
        int nf = lane >> 4, lr = lane & 15;
        int col = 64 * wave + 16 * nf + lr;
        double ssum = shred[(wave * 4 + nf) * 16 + lr] +
                      shred[((4 + wave) * 4 + nf) * 16 + lr];
        double qsum = shred[512 + (wave * 4 + nf) * 16 + lr] +
                      shred[512 + ((4 + wave) * 4 + nf) * 16 + lr];
        // [block][channel] layout: contiguous 4KB per block
        partial[(size_t)blockIdx.x * 512 + col] = ssum;
        partial[(size_t)blockIdx.x * 512 + 256 + col] = qsum;
    }
}

// ------- GEMM2 fused (round 11): BN+LIF in staging, then spikes @ W2 (bf16x3) --------
// Block covers rows {t*(M/4) + bn0 + i : t=0..3, i=0..31} (local row L = t*32+i) so
// the LIF recurrence over t is thread-local during staging. K-loop = r5 config.
__global__ __launch_bounds__(512) void gemm2_fused(const float* __restrict__ h,
                                                   const float2* __restrict__ ss1,
                                                   const unsigned short* __restrict__ Bt,
                                                   const float* __restrict__ bias,
                                                   float* __restrict__ C,
                                                   double* __restrict__ partial,
                                                   int bnRows) {
    __shared__ __align__(16) unsigned short Asw[128 * 256];  // 64 KB bf16 spikes
    const int bn0 = blockIdx.x * 32;
    const int tid = threadIdx.x;
    const int lane = tid & 63;
    const int wave = tid >> 6;   // 0..7
    const int wr = wave >> 2;    // 0..1
    const int wc = wave & 3;     // 0..3
    const int lrow = lane & 15, lchunk = lane >> 4;

    const unsigned short* Bbase =
        Bt + ((size_t)(64 * wc + lrow)) * 256 + lchunk * 8;

    bf16x8 bb[2][12];
#define LOADB(buf, kk)                                                        \
    _Pragma("unroll") for (int t = 0; t < 3; ++t)                             \
    _Pragma("unroll") for (int nf = 0; nf < 4; ++nf)                          \
        bb[buf][t * 4 + nf] = *(const bf16x8*)(Bbase + (size_t)t * 65536 +    \
                                               nf * 4096 + (kk) * 32);

    LOADB(0, 0)  // in flight during staging

    // ---- stage: h fp32 -> BN(ss1) -> LIF over t=0..3 -> bf16 spikes in swizzled LDS -
    {
#pragma unroll
        for (int it = 0; it < 4; ++it) {
            int slot = it * 512 + tid;        // 2048 slots: bn(32) x colq(64)
            int bn = slot >> 6;
            int colq = slot & 63;
            int c0 = colq * 4;
            float2 p0 = ss1[c0], p1 = ss1[c0 + 1], p2 = ss1[c0 + 2], p3 = ss1[c0 + 3];
            float4 v = make_float4(0.f, 0.f, 0.f, 0.f);
#pragma unroll
            for (int t = 0; t < 4; ++t) {
                float4 hv = *(const float4*)(h + ((size_t)t * bnRows + bn0 + bn) * 256 + c0);
                float x0 = hv.x * p0.x + p0.y;
                float x1 = hv.y * p1.x + p1.y;
                float x2 = hv.z * p2.x + p2.y;
                float x3 = hv.w * p3.x + p3.y;
                v.x = (v.x + x0) * 0.5f;
                v.y = (v.y + x1) * 0.5f;
                v.z = (v.z + x2) * 0.5f;
                v.w = (v.w + x3) * 0.5f;
                ushort4 sp;
                sp.x = (v.x >= 1.0f) ? 0x3F80 : 0;
                sp.y = (v.y >= 1.0f) ? 0x3F80 : 0;
                sp.z = (v.z >= 1.0f) ? 0x3F80 : 0;
                sp.w = (v.w >= 1.0f) ? 0x3F80 : 0;
                v.x = (v.x >= 1.0f) ? 0.0f : v.x;
                v.y = (v.y >= 1.0f) ? 0.0f : v.y;
                v.z = (v.z >= 1.0f) ? 0.0f : v.z;
                v.w = (v.w >= 1.0f) ? 0.0f : v.w;
                unsigned row = (unsigned)(t * 32 + bn);
                unsigned off = (row * 512u + (unsigned)colq * 8u) ^ ((row & 7u) << 4);
                *(ushort4*)((char*)Asw + off) = sp;
            }
        }
    }
    __syncthreads();

    f32x4 acc[4][4] = {};

#pragma unroll
    for (int k0 = 0; k0 < 8; ++k0) {
        const int cur = k0 & 1;
        if (k0 < 7) { LOADB(cur ^ 1, k0 + 1) }
        bf16x8 af[4];
#pragma unroll
        for (int mf = 0; mf < 4; ++mf) {
            unsigned r = (unsigned)(64 * wr + 16 * mf + lrow);
            unsigned off = r * 512u + (unsigned)(k0 * 64 + lchunk * 16);
            off ^= ((r & 7u) << 4);
            af[mf] = *(const bf16x8*)((const char*)Asw + off);
        }
#pragma unroll
        for (int t = 0; t < 3; ++t)
#pragma unroll
            for (int nf = 0; nf < 4; ++nf)
#pragma unroll
                for (int mf = 0; mf < 4; ++mf)
                    acc[mf][nf] = __builtin_amdgcn_mfma_f32_16x16x32_bf16(
                        af[mf], bb[cur][t * 4 + nf], acc[mf][nf], 0, 0, 0);
    }
#undef LOADB

    // ---- C write (remap local row L -> t*bnRows + bn0 + (L&31)) + column sums ----
    double s[4], q[4];
#pragma unroll
    for (int nf = 0; nf < 4; ++nf) {
        int col = 64 * wc + 16 * nf + lrow;
        float bvv = bias[col];
        double ss = 0.0, qq = 0.0;
#pragma unroll
        for (int mf = 0; mf < 4; ++mf) {
            int Lbase = 64 * wr + 16 * mf + 4 * lchunk;
#pragma unroll
            for (int e = 0; e < 4; ++e) {
                int L = Lbase + e;
                size_t G = (size_t)(L >> 5) * bnRows + bn0 + (L & 31);
                float hv = acc[mf][nf][e] + bvv;
                C[G * 256 + col] = hv;
                ss += (double)hv;
                qq += (double)hv * (double)hv;
            }
        }
        s[nf] = ss;
        q[nf] = qq;
    }
#pragma unroll
    for (int nf = 0; nf < 4; ++nf) {
        s[nf] += __shfl_xor(s[nf], 16);
        s[nf] += __shfl_xor(s[nf], 32);
        q[nf] += __shfl_xor(q[nf], 16);
        q[nf] += __shfl_xor(q[nf], 32);
    }
    __syncthreads();
    double* shred = (double*)Asw;
    if (lane < 16) {
#pragma unroll
        for (int nf = 0; nf < 4; ++nf) {
            shred[(wave * 4 + nf) * 16 + lane] = s[nf];
            shred[512 + (wave * 4 + nf) * 16 + lane] = q[nf];
        }
    }
    __syncthreads();
    if (wave < 4) {
        int nf = lane >> 4, lr = lane & 15;
        int col = 64 * wave + 16 * nf + lr;
        double ssum = shred[(wave * 4 + nf) * 16 + lr] +
                      shred[((4 + wave) * 4 + nf) * 16 + lr];
        double qsum = shred[512 + (wave * 4 + nf) * 16 + lr] +
                      shred[512 + ((4 + wave) * 4 + nf) * 16 + lr];
        partial[(size_t)blockIdx.x * 512 + col] = ssum;
        partial[(size_t)blockIdx.x * 512 + 256 + col] = qsum;
    }
}

// 256 blocks (one per channel) x 256 threads; [block][channel] layout, coalesced.
__global__ __launch_bounds__(256) void finalize_stats(const double* __restrict__ partial,
                                                      const float* __restrict__ gamma,
                                                      const float* __restrict__ beta,
                                                      float2* __restrict__ ss,
                                                      int nblocks, double invM) {
    const int c = blockIdx.x;
    const int t = threadIdx.x;
    __shared__ double sh[256];
    __shared__ double sh2[256];
    double s = 0.0, s2 = 0.0;
    for (int b = t; b < nblocks; b += 256) {
        s += partial[(size_t)b * 512 + c];
        s2 += partial[(size_t)b * 512 + 256 + c];
    }
    sh[t] = s;
    sh2[t] = s2;
    __syncthreads();
#pragma unroll
    for (int off = 128; off > 0; off >>= 1) {
        if (t < off) {
            sh[t] += sh[t + off];
            sh2[t] += sh2[t + off];
        }
        __syncthreads();
    }
    if (t == 0) {
        double mu = sh[0] * invM;
        double var = sh2[0] * invM - mu * mu;
        double rstd = 1.0 / sqrt(var + 1e-5);
        double sc = (double)gamma[c] * rstd;
        ss[c] = make_float2((float)sc, (float)((double)beta[c] - mu * sc));
    }
}

// ---------------- Fused BN(affine) + multi-step LIF over T=4 (final output) ----------
__global__ __launch_bounds__(256) void bnlif_f32(const float* __restrict__ h,
                                                 const float2* __restrict__ ss,
                                                 float* __restrict__ out,
                                                 int slab4) {
    int t4 = blockIdx.x * 256 + threadIdx.x;
    if (t4 >= slab4) return;
    size_t idx = (size_t)t4 * 4;
    int c0 = (int)(idx & 255);
    float2 p0 = ss[c0], p1 = ss[c0 + 1], p2 = ss[c0 + 2], p3 = ss[c0 + 3];
    size_t slab = (size_t)slab4 * 4;
    float4 v = make_float4(0.f, 0.f, 0.f, 0.f);
#pragma unroll
    for (int t = 0; t < 4; ++t) {
        float4 hv = *(const float4*)(h + (size_t)t * slab + idx);
        float x0 = hv.x * p0.x + p0.y;
        float x1 = hv.y * p1.x + p1.y;
        float x2 = hv.z * p2.x + p2.y;
        float x3 = hv.w * p3.x + p3.y;
        v.x = (v.x + x0) * 0.5f;
        v.y = (v.y + x1) * 0.5f;
        v.z = (v.z + x2) * 0.5f;
        v.w = (v.w + x3) * 0.5f;
        float4 sp;
        sp.x = (v.x >= 1.0f) ? 1.0f : 0.0f;
        sp.y = (v.y >= 1.0f) ? 1.0f : 0.0f;
        sp.z = (v.z >= 1.0f) ? 1.0f : 0.0f;
        sp.w = (v.w >= 1.0f) ? 1.0f : 0.0f;
        v.x = (v.x >= 1.0f) ? 0.0f : v.x;
        v.y = (v.y >= 1.0f) ? 0.0f : v.y;
        v.z = (v.z >= 1.0f) ? 0.0f : v.z;
        v.w = (v.w >= 1.0f) ? 0.0f : v.w;
        *(float4*)(out + (size_t)t * slab + idx) = sp;
    }
}

extern "C" void kernel_launch(void* const* d_in, const int* in_sizes, int n_in,
                              void* d_out, int out_size, void* d_ws, size_t ws_size,
                              hipStream_t stream) {
    const float* x  = (const float*)d_in[0];
    const float* W1 = (const float*)d_in[1];
    const float* b1 = (const float*)d_in[2];
    const float* g1 = (const float*)d_in[3];
    const float* be1 = (const float*)d_in[4];
    const float* W2 = (const float*)d_in[5];
    const float* b2 = (const float*)d_in[6];
    const float* g2 = (const float*)d_in[7];
    const float* be2 = (const float*)d_in[8];
    float* out = (float*)d_out;

    const int M = in_sizes[0] / 256;            // 131072
    const int bnRows = M / 4;                   // 32768
    const size_t hBytes = (size_t)M * 256 * 4;  // 128 MiB

    char* ws = (char*)d_ws;
    float* h = (float*)ws;                                   // 128 MiB fp32 (h / o)
    double* partial = (double*)(ws + hBytes);                // 4 MiB ([block][512])
    unsigned short* W2catT = (unsigned short*)(ws + hBytes + (size_t)1024 * 512 * 8);
    float2* ss1 = (float2*)((char*)W2catT + 3 * 256 * 256 * 2);
    float2* ss2 = ss1 + 256;
    _Float16* W1hiT = (_Float16*)(ss2 + 256);
    _Float16* W1loT = W1hiT + 256 * 256;

    const int slab4 = M * 16;
    const double invM = 1.0 / (double)M;

    dim3 blk(256);

    // weight splits
    split_w1<<<dim3(256), blk, 0, stream>>>(W1, W1hiT, W1loT);
    split_w2<<<dim3(256), blk, 0, stream>>>(W2, W2catT);

    // ---- layer 1 (fp16x2-split MFMA GEMM, BM=128 + fused stats) ----
    gemm1_mfma<<<dim3(M / 128), dim3(512), 0, stream>>>(x, W1hiT, W1loT, b1, h, partial);
    finalize_stats<<<dim3(256), blk, 0, stream>>>(partial, g1, be1, ss1, M / 128, invM);

    // ---- layer 2 (BN+LIF fused staging; bf16x3 MFMA GEMM; fused stats) ----
    gemm2_fused<<<dim3(bnRows / 32), dim3(512), 0, stream>>>(h, ss1, W2catT, b2, h, partial, bnRows);
    finalize_stats<<<dim3(256), blk, 0, stream>>>(partial, g2, be2, ss2, bnRows / 32, invM);
    bnlif_f32<<<dim3(slab4 / 256), blk, 0, stream>>>(h, ss2, out, slab4);
}